// Round 11
// baseline (72.432 us; speedup 1.0000x reference)
//
#include <hip/hip_runtime.h>

// Problem constants (from reference)
#define NNODES 10000
#define DDEG   64
#define NEDGES 32768
#define FIN    64
#define HID    256

typedef __attribute__((ext_vector_type(8))) __bf16 bf16x8;
typedef __attribute__((ext_vector_type(4))) float  f32x4;

__device__ __forceinline__ unsigned short f2bf(float f) {
    unsigned x = __float_as_uint(f);
    return (unsigned short)((x + 0x7FFFu + ((x >> 16) & 1u)) >> 16);  // RNE
}
__device__ __forceinline__ float b2f(unsigned short u) {
    return __uint_as_float(((unsigned)u) << 16);
}

// Blocked transposed-weight layout (bf16): WT[k>>5][n][k&31], tile = 8192 elems (16KB).
#define OFF_XIJ1 0        // K=64  : tiles 0..1
#define OFF_XIJ2 16384    // K=256 : tiles 2..9
#define OFF_XCN1 81920    // tiles 10..11
#define OFF_XCN2 98304    // tiles 12..19
#define OFF_XCN3 163840   // tiles 20..27
#define OFF_LIN1 229376   // tiles 28..35
#define WT_TOTAL 294912
#define NTILES   36

__host__ __device__ constexpr int tile_off(int t) {
    return t < 2  ? OFF_XIJ1 + t * 8192
         : t < 10 ? OFF_XIJ2 + (t - 2) * 8192
         : t < 12 ? OFF_XCN1 + (t - 10) * 8192
         : t < 20 ? OFF_XCN2 + (t - 12) * 8192
         : t < 28 ? OFF_XCN3 + (t - 20) * 8192
         :          OFF_LIN1 + (t - 28) * 8192;
}

// Weight prep: fp32 W[K,256] -> blocked bf16 WT (one small launch).
__global__ __launch_bounds__(256) void prep_k(const float* __restrict__ xij_w1,
                                              const float* __restrict__ xij_w2,
                                              const float* __restrict__ xcn_w1,
                                              const float* __restrict__ xcn_w2,
                                              const float* __restrict__ xcn_w3,
                                              const float* __restrict__ lin_w1,
                                              unsigned short* __restrict__ WT) {
    int idx = blockIdx.x * 256 + threadIdx.x;          // grid 1152
    const float* src;
    int r;
    if (idx < OFF_XIJ2)      { r = idx - OFF_XIJ1; src = xij_w1; }
    else if (idx < OFF_XCN1) { r = idx - OFF_XIJ2; src = xij_w2; }
    else if (idx < OFF_XCN2) { r = idx - OFF_XCN1; src = xcn_w1; }
    else if (idx < OFF_XCN3) { r = idx - OFF_XCN2; src = xcn_w2; }
    else if (idx < OFF_LIN1) { r = idx - OFF_XCN3; src = xcn_w3; }
    else                     { r = idx - OFF_LIN1; src = lin_w1; }
    int kb  = r >> 13;
    int n   = (r & 8191) >> 5;
    int klo = r & 31;
    WT[idx] = f2bf(src[(kb * 32 + klo) * HID + n]);
}

// ---- async global->LDS (LDS dest = wave-uniform base + lane*16B) ----
__device__ __forceinline__ void gll16(const unsigned short* g, unsigned short* l) {
    __builtin_amdgcn_global_load_lds(
        (const __attribute__((address_space(1))) unsigned int*)g,
        (__attribute__((address_space(3))) unsigned int*)l, 16, 0, 0);
}
// 16KB tile with 512 threads: 2 gll16/thread (vmcnt cost = 2 per wave)
__device__ __forceinline__ void stage_tile(const unsigned short* g, unsigned short* l,
                                           int tid, int wv) {
#pragma unroll
    for (int c = 0; c < 2; ++c)
        gll16(g + c * 4096 + tid * 8, l + c * 4096 + wv * 512);
}

// One phase of the 36-tile stream; 3-slot ring, ONE barrier per step.
// Step t: wait vmcnt(2) (tile t landed; t+1 in flight) + lgkmcnt(0) (prior epilogue
// ds_writes visible); barrier; ds_read A(4)+B(4); 16 MFMA; stage tile t+2 into slot
// (t+2)%3 (= slot last read at step t-1 -> fenced by this step's barrier).
// acc[4][4]: wave tile rows r0..r0+64, cols col0..col0+64.
template <int T0, int NT, int LDA>
__device__ __forceinline__ void run_phase(const unsigned short* As,
                                          unsigned short* ring,
                                          const unsigned short* __restrict__ WT,
                                          int lr, int lg, int col0, int r0,
                                          int tid, int wv, f32x4 acc[4][4]) {
#pragma unroll
    for (int m = 0; m < 4; ++m)
#pragma unroll
        for (int n = 0; n < 4; ++n) acc[m][n] = (f32x4){0.f, 0.f, 0.f, 0.f};
    const int sw = (lr & 7) << 3;
#pragma unroll
    for (int s = 0; s < NT; ++s) {
        const int t = T0 + s;
        if (t < NTILES - 1)
            asm volatile("s_waitcnt vmcnt(2) lgkmcnt(0)" ::: "memory");
        else
            asm volatile("s_waitcnt vmcnt(0) lgkmcnt(0)" ::: "memory");
        __builtin_amdgcn_s_barrier();
        const unsigned short* cur = ring + (t % 3) * 8192;
        bf16x8 a[4], b[4];
#pragma unroll
        for (int n = 0; n < 4; ++n)
            b[n] = *reinterpret_cast<const bf16x8*>(&cur[(col0 + n * 16 + lr) * 32 + 8 * lg]);
#pragma unroll
        for (int m = 0; m < 4; ++m)
            a[m] = *reinterpret_cast<const bf16x8*>(
                &As[(r0 + m * 16 + lr) * LDA + ((s * 32 + 8 * lg) ^ sw)]);
        __builtin_amdgcn_s_setprio(1);
#pragma unroll
        for (int m = 0; m < 4; ++m)
#pragma unroll
            for (int n = 0; n < 4; ++n)
                acc[m][n] = __builtin_amdgcn_mfma_f32_16x16x32_bf16(a[m], b[n], acc[m][n], 0, 0, 0);
        __builtin_amdgcn_s_setprio(0);
        if (t + 2 < NTILES)
            stage_tile(WT + tile_off(t + 2), ring + ((t + 2) % 3) * 8192, tid, wv);
    }
}

// Fully fused kernel: edge stage + 6-layer MLP chain per 128-edge block.
// Grid 256 = exactly 1 block/CU. 8 waves: wr=wv>>2 rows wr*64..+64, wc=wv&3 cols wc*64..+64.
// D-frag lane l: row = r0 + m*16 + 4*(l>>4) + i, col = col0 + n*16 + (l&15).
__global__ __launch_bounds__(512, 1) void fused_k(const float* __restrict__ x,
                                                  const int* __restrict__ adj,
                                                  const int* __restrict__ tar,
                                                  const unsigned short* __restrict__ WT,
                                                  const float* __restrict__ xij_b1,
                                                  const float* __restrict__ xij_b2,
                                                  const float* __restrict__ xcn_b1,
                                                  const float* __restrict__ xcn_b2,
                                                  const float* __restrict__ xcn_b3,
                                                  const float* __restrict__ lin_b1,
                                                  const float* __restrict__ lin_w2,
                                                  const float* __restrict__ lin_b2,
                                                  const float* __restrict__ beta,
                                                  float* __restrict__ out) {
    __shared__ unsigned short sXij[128 * 64];   // 16 KB, swizzled (later aliased as sRed)
    __shared__ unsigned short sXcn[128 * 64];   // 16 KB, swizzled
    __shared__ unsigned short sH[128 * 256];    // 64 KB activation (in-place reuse)
    __shared__ unsigned short sB[3 * 8192];     // 48 KB weight ring
    // total 144 KB -> 1 block/CU

    const int tid  = threadIdx.x;
    const int wv   = tid >> 6;
    const int lane = tid & 63;
    const int lr   = lane & 15;
    const int lg   = lane >> 4;
    const int r0   = (wv >> 2) * 64;
    const int col0 = (wv & 3) * 64;
    const int row0 = blockIdx.x * 128;

    // ring tiles 0,1 staged first: in flight during the edge phase (edge loads are
    // newer in the vmcnt FIFO, so any edge-load wait completes these first).
    stage_tile(WT + tile_off(0), sB, tid, wv);
    stage_tile(WT + tile_off(1), sB + 8192, tid, wv);
    const float betaf = beta[0];

    // ---- edge stage: 16 edges per wave, 2-deep prefetch; write LDS swizzled ----
    {
        const int e0 = row0 + wv * 16;
        int   ic = tar[e0];
        int   jc = tar[NEDGES + e0];
        int   ni_c = adj[ic * DDEG + lane];
        int   nj_c = adj[jc * DDEG + lane];
        float xi_c = x[ic * FIN + lane];
        float xj_c = x[jc * FIN + lane];
        for (int t = 0; t < 16; ++t) {
            int ni = ni_c, nj = nj_c;
            float xi = xi_c, xj = xj_c;
            if (t < 15) {
                int e = e0 + t + 1;
                int i2 = tar[e];
                int j2 = tar[NEDGES + e];
                ni_c = adj[i2 * DDEG + lane];
                nj_c = adj[j2 * DDEG + lane];
                xi_c = x[i2 * FIN + lane];
                xj_c = x[j2 * FIN + lane];
            }
            bool found = false;
#pragma unroll
            for (int b = 0; b < 64; ++b)
                found |= (ni == (int)__builtin_amdgcn_readlane(nj, b));
            unsigned long long m = __ballot(found);
            float acc = 0.f;
            while (m) {
                int a = __ffsll(m) - 1;
                m &= m - 1;
                int r = (int)__builtin_amdgcn_readlane(ni, a);
                acc += x[r * FIN + lane];
            }
            int el = wv * 16 + t;
            int sidx = el * FIN + (lane ^ ((el & 7) << 3));
            sXij[sidx] = f2bf(xi * xj);
            sXcn[sidx] = f2bf(acc);
        }
    }
    // P1 step0's lgkmcnt(0)+barrier makes all waves' sXij/sXcn writes visible.

    f32x4 acc[4][4];
    float bl[4];

    // ---- P1: h1 = relu(xij @ xij_w1 + b1) -> sH (sH not read in P1: no hazard) ----
    run_phase<0, 2, 64>(sXij, sB, WT, lr, lg, col0, r0, tid, wv, acc);
#pragma unroll
    for (int n = 0; n < 4; ++n) bl[n] = xij_b1[col0 + n * 16 + lr];
#pragma unroll
    for (int m = 0; m < 4; ++m)
#pragma unroll
        for (int n = 0; n < 4; ++n)
#pragma unroll
            for (int i = 0; i < 4; ++i) {
                int row = r0 + m * 16 + 4 * lg + i;
                int col = col0 + n * 16 + lr;
                sH[row * HID + (col ^ ((row & 7) << 3))] = f2bf(fmaxf(acc[m][n][i] + bl[n], 0.f));
            }

    // ---- P2: h_ij = h1 @ xij_w2 + b2 -> registers (packed bf16, 32 VGPR) ----
    run_phase<2, 8, 256>(sH, sB, WT, lr, lg, col0, r0, tid, wv, acc);
#pragma unroll
    for (int n = 0; n < 4; ++n) bl[n] = xij_b2[col0 + n * 16 + lr];
    unsigned hij_lo[4][4], hij_hi[4][4];
#pragma unroll
    for (int m = 0; m < 4; ++m)
#pragma unroll
        for (int n = 0; n < 4; ++n) {
            hij_lo[m][n] = ((unsigned)f2bf(acc[m][n][1] + bl[n]) << 16) | f2bf(acc[m][n][0] + bl[n]);
            hij_hi[m][n] = ((unsigned)f2bf(acc[m][n][3] + bl[n]) << 16) | f2bf(acc[m][n][2] + bl[n]);
        }

    // ---- P3: t1 = relu(xcn @ xcn_w1 + b1) -> sH (P2 readers finished pre-P3 barriers) ----
    run_phase<10, 2, 64>(sXcn, sB, WT, lr, lg, col0, r0, tid, wv, acc);
#pragma unroll
    for (int n = 0; n < 4; ++n) bl[n] = xcn_b1[col0 + n * 16 + lr];
#pragma unroll
    for (int m = 0; m < 4; ++m)
#pragma unroll
        for (int n = 0; n < 4; ++n)
#pragma unroll
            for (int i = 0; i < 4; ++i) {
                int row = r0 + m * 16 + 4 * lg + i;
                int col = col0 + n * 16 + lr;
                sH[row * HID + (col ^ ((row & 7) << 3))] = f2bf(fmaxf(acc[m][n][i] + bl[n], 0.f));
            }

    // ---- P4: t2 = relu(t1 @ xcn_w2 + b2) -> sH IN PLACE: barrier before writes ----
    run_phase<12, 8, 256>(sH, sB, WT, lr, lg, col0, r0, tid, wv, acc);
    asm volatile("s_waitcnt lgkmcnt(0)" ::: "memory");
    __builtin_amdgcn_s_barrier();   // all waves' t1 reads done before overwrite
#pragma unroll
    for (int n = 0; n < 4; ++n) bl[n] = xcn_b2[col0 + n * 16 + lr];
#pragma unroll
    for (int m = 0; m < 4; ++m)
#pragma unroll
        for (int n = 0; n < 4; ++n)
#pragma unroll
            for (int i = 0; i < 4; ++i) {
                int row = r0 + m * 16 + 4 * lg + i;
                int col = col0 + n * 16 + lr;
                sH[row * HID + (col ^ ((row & 7) << 3))] = f2bf(fmaxf(acc[m][n][i] + bl[n], 0.f));
            }

    // ---- P5: u = (t2 @ xcn_w3 + b3) * beta + h_ij -> sH IN PLACE ----
    run_phase<20, 8, 256>(sH, sB, WT, lr, lg, col0, r0, tid, wv, acc);
    asm volatile("s_waitcnt lgkmcnt(0)" ::: "memory");
    __builtin_amdgcn_s_barrier();
#pragma unroll
    for (int n = 0; n < 4; ++n) bl[n] = xcn_b3[col0 + n * 16 + lr];
#pragma unroll
    for (int m = 0; m < 4; ++m)
#pragma unroll
        for (int n = 0; n < 4; ++n) {
            float h0 = b2f((unsigned short)(hij_lo[m][n] & 0xFFFF));
            float h1 = b2f((unsigned short)(hij_lo[m][n] >> 16));
            float h2 = b2f((unsigned short)(hij_hi[m][n] & 0xFFFF));
            float h3 = b2f((unsigned short)(hij_hi[m][n] >> 16));
            float v0 = (acc[m][n][0] + bl[n]) * betaf + h0;
            float v1 = (acc[m][n][1] + bl[n]) * betaf + h1;
            float v2 = (acc[m][n][2] + bl[n]) * betaf + h2;
            float v3 = (acc[m][n][3] + bl[n]) * betaf + h3;
            int rb = r0 + m * 16 + 4 * lg;
            int col = col0 + n * 16 + lr;
            sH[(rb + 0) * HID + (col ^ (((rb + 0) & 7) << 3))] = f2bf(v0);
            sH[(rb + 1) * HID + (col ^ (((rb + 1) & 7) << 3))] = f2bf(v1);
            sH[(rb + 2) * HID + (col ^ (((rb + 2) & 7) << 3))] = f2bf(v2);
            sH[(rb + 3) * HID + (col ^ (((rb + 3) & 7) << 3))] = f2bf(v3);
        }

    // ---- P6: out = relu(u @ lin_w1 + lb1) . lin_w2 + lb2 (writes sRed in dead sXij) ----
    run_phase<28, 8, 256>(sH, sB, WT, lr, lg, col0, r0, tid, wv, acc);
#pragma unroll
    for (int n = 0; n < 4; ++n) bl[n] = lin_b1[col0 + n * 16 + lr];
    float w2l[4];
#pragma unroll
    for (int n = 0; n < 4; ++n) w2l[n] = lin_w2[col0 + n * 16 + lr];
    float* sRed = (float*)sXij;   // 4 col-groups x 128 rows of f32 (2 KB) in dead sXij
#pragma unroll
    for (int m = 0; m < 4; ++m) {
        float p[4] = {0.f, 0.f, 0.f, 0.f};
#pragma unroll
        for (int n = 0; n < 4; ++n)
#pragma unroll
            for (int i = 0; i < 4; ++i)
                p[i] += fmaxf(acc[m][n][i] + bl[n], 0.f) * w2l[n];
#pragma unroll
        for (int i = 0; i < 4; ++i) {
            float s = p[i];
            s += __shfl_xor(s, 1);
            s += __shfl_xor(s, 2);
            s += __shfl_xor(s, 4);
            s += __shfl_xor(s, 8);
            if (lr == 0) sRed[(wv & 3) * 128 + r0 + m * 16 + 4 * lg + i] = s;
        }
    }
    __syncthreads();
    if (tid < 128)
        out[row0 + tid] = sRed[tid] + sRed[128 + tid] + sRed[256 + tid] + sRed[384 + tid] + lin_b2[0];
}

extern "C" void kernel_launch(void* const* d_in, const int* in_sizes, int n_in,
                              void* d_out, int out_size, void* d_ws, size_t ws_size,
                              hipStream_t stream) {
    const float* x      = (const float*)d_in[0];
    const int*   adj    = (const int*)d_in[1];
    const int*   tar    = (const int*)d_in[2];
    const float* beta   = (const float*)d_in[3];
    const float* xcn_w1 = (const float*)d_in[4];
    const float* xcn_b1 = (const float*)d_in[5];
    const float* xcn_w2 = (const float*)d_in[6];
    const float* xcn_b2 = (const float*)d_in[7];
    const float* xcn_w3 = (const float*)d_in[8];
    const float* xcn_b3 = (const float*)d_in[9];
    const float* xij_w1 = (const float*)d_in[10];
    const float* xij_b1 = (const float*)d_in[11];
    const float* xij_w2 = (const float*)d_in[12];
    const float* xij_b2 = (const float*)d_in[13];
    const float* lin_w1 = (const float*)d_in[14];
    const float* lin_b1 = (const float*)d_in[15];
    const float* lin_w2 = (const float*)d_in[16];
    const float* lin_b2 = (const float*)d_in[17];

    unsigned short* WT = (unsigned short*)d_ws;   // 576 KiB

    prep_k<<<WT_TOTAL / 256, 256, 0, stream>>>(xij_w1, xij_w2, xcn_w1, xcn_w2, xcn_w3, lin_w1, WT);
    fused_k<<<NEDGES / 128, 512, 0, stream>>>(x, adj, tar, WT,
                                              xij_b1, xij_b2, xcn_b1, xcn_b2, xcn_b3,
                                              lin_b1, lin_w2, lin_b2, beta, (float*)d_out);
}

// Round 12
// 62.598 us; speedup vs baseline: 1.1571x; 1.1571x over previous
//
#include <hip/hip_runtime.h>

// Problem constants (from reference)
#define NNODES 10000
#define DDEG   64
#define NEDGES 32768
#define FIN    64
#define HID    256

typedef __attribute__((ext_vector_type(8))) __bf16 bf16x8;
typedef __attribute__((ext_vector_type(4))) float  f32x4;

__device__ __forceinline__ unsigned short f2bf(float f) {
    unsigned x = __float_as_uint(f);
    return (unsigned short)((x + 0x7FFFu + ((x >> 16) & 1u)) >> 16);  // RNE
}
__device__ __forceinline__ float b2f(unsigned short u) {
    return __uint_as_float(((unsigned)u) << 16);
}

// Blocked transposed-weight layout (bf16): WT[k>>5][n][k&31], tile = 8192 elems (16KB).
#define OFF_XIJ1 0        // K=64  : tiles 0..1
#define OFF_XIJ2 16384    // K=256 : tiles 2..9
#define OFF_XCN1 81920    // tiles 10..11
#define OFF_XCN2 98304    // tiles 12..19
#define OFF_XCN3 163840   // tiles 20..27
#define OFF_LIN1 229376   // tiles 28..35
#define WT_TOTAL 294912
#define NTILES   36

__host__ __device__ constexpr int tile_off(int t) {
    return t < 2  ? OFF_XIJ1 + t * 8192
         : t < 10 ? OFF_XIJ2 + (t - 2) * 8192
         : t < 12 ? OFF_XCN1 + (t - 10) * 8192
         : t < 20 ? OFF_XCN2 + (t - 12) * 8192
         : t < 28 ? OFF_XCN3 + (t - 20) * 8192
         :          OFF_LIN1 + (t - 28) * 8192;
}

// ---- async global->LDS (LDS dest = wave-uniform base + lane*16B) ----
__device__ __forceinline__ void gll16(const unsigned short* g, unsigned short* l) {
    __builtin_amdgcn_global_load_lds(
        (const __attribute__((address_space(1))) unsigned int*)g,
        (__attribute__((address_space(3))) unsigned int*)l, 16, 0, 0);
}
// 16KB tile with 512 threads: 2 gll16/thread (vmcnt cost = 2 per wave)
__device__ __forceinline__ void stage_tile(const unsigned short* g, unsigned short* l,
                                           int tid, int wv) {
#pragma unroll
    for (int c = 0; c < 2; ++c)
        gll16(g + c * 4096 + tid * 8, l + c * 4096 + wv * 512);
}

// Edge stage (1 edge per wave, latency TLP-hidden at 8192 blocks) + weight-prep piggyback.
// xij/xcn written PRE-SWIZZLED (elem ^= (row&7)<<3) so linear global_load_lds staging
// lands in the swizzled layout the mlp A-fragment ds_reads expect.
__global__ __launch_bounds__(256) void edge_prep_k(const float* __restrict__ x,
                                                   const int* __restrict__ adj,
                                                   const int* __restrict__ tar,
                                                   const float* __restrict__ xij_w1,
                                                   const float* __restrict__ xij_w2,
                                                   const float* __restrict__ xcn_w1,
                                                   const float* __restrict__ xcn_w2,
                                                   const float* __restrict__ xcn_w3,
                                                   const float* __restrict__ lin_w1,
                                                   unsigned short* __restrict__ WT,
                                                   unsigned short* __restrict__ xij_g,
                                                   unsigned short* __restrict__ xcn_g) {
    const int wv   = threadIdx.x >> 6;
    const int lane = threadIdx.x & 63;
    const int e    = blockIdx.x * 4 + wv;      // grid = NEDGES/4 = 8192

    int i = tar[e];
    int j = tar[NEDGES + e];
    int ni = adj[i * DDEG + lane];
    int nj = adj[j * DDEG + lane];
    float xi = x[i * FIN + lane];
    float xj = x[j * FIN + lane];

    bool found = false;
#pragma unroll
    for (int b = 0; b < 64; ++b)
        found |= (ni == (int)__builtin_amdgcn_readlane(nj, b));
    unsigned long long m = __ballot(found);

    float acc = 0.f;
    while (m) {
        int a = __ffsll(m) - 1;
        m &= m - 1;
        int r = (int)__builtin_amdgcn_readlane(ni, a);
        acc += x[r * FIN + lane];
    }
    int sl = lane ^ ((e & 7) << 3);            // pre-swizzle (row&7 == e&7)
    xij_g[(size_t)e * FIN + sl] = f2bf(xi * xj);
    xcn_g[(size_t)e * FIN + sl] = f2bf(acc);

    // ---- weight-prep piggyback: fp32 W[K,256] -> blocked bf16 WT ----
    if (blockIdx.x < WT_TOTAL / 256) {
        int idx = blockIdx.x * 256 + threadIdx.x;
        const float* src;
        int r;
        if (idx < OFF_XIJ2)      { r = idx - OFF_XIJ1; src = xij_w1; }
        else if (idx < OFF_XCN1) { r = idx - OFF_XIJ2; src = xij_w2; }
        else if (idx < OFF_XCN2) { r = idx - OFF_XCN1; src = xcn_w1; }
        else if (idx < OFF_XCN3) { r = idx - OFF_XCN2; src = xcn_w2; }
        else if (idx < OFF_LIN1) { r = idx - OFF_XCN3; src = xcn_w3; }
        else                     { r = idx - OFF_LIN1; src = lin_w1; }
        int kb  = r >> 13;
        int n   = (r & 8191) >> 5;
        int klo = r & 31;
        WT[idx] = f2bf(src[(kb * 32 + klo) * HID + n]);
    }
}

// One phase of the 36-tile stream; 3-slot ring, ONE barrier per step, stage at top.
// Step t: wait vmcnt(2) (tile t landed; t+1 in flight) + lgkmcnt(0) (own prior ds ops
// drained BEFORE the barrier -> cross-wave WAR on ring slots and sH is safe); barrier;
// stage tile t+2 into slot (t+2)%3 (last read at step t-1, fenced by this barrier);
// ds_read A(4)+B(4); 16 MFMA (setprio). Hazards: RAW on tile t via vmcnt+barrier;
// WAR on slot (t+2)%3 via lgkm0+barrier. acc[4][4]: rows r0..+64, cols col0..+64.
template <int T0, int NT, int LDA>
__device__ __forceinline__ void run_phase(const unsigned short* As,
                                          unsigned short* ring,
                                          const unsigned short* __restrict__ WT,
                                          int lr, int lg, int col0, int r0,
                                          int tid, int wv, f32x4 acc[4][4]) {
#pragma unroll
    for (int m = 0; m < 4; ++m)
#pragma unroll
        for (int n = 0; n < 4; ++n) acc[m][n] = (f32x4){0.f, 0.f, 0.f, 0.f};
    const int sw = (lr & 7) << 3;
#pragma unroll
    for (int s = 0; s < NT; ++s) {
        const int t = T0 + s;
        if (t < NTILES - 1)
            asm volatile("s_waitcnt vmcnt(2) lgkmcnt(0)" ::: "memory");
        else
            asm volatile("s_waitcnt vmcnt(0) lgkmcnt(0)" ::: "memory");
        __builtin_amdgcn_s_barrier();
        if (t + 2 < NTILES)
            stage_tile(WT + tile_off(t + 2), ring + ((t + 2) % 3) * 8192, tid, wv);
        const unsigned short* cur = ring + (t % 3) * 8192;
        bf16x8 a[4], b[4];
#pragma unroll
        for (int n = 0; n < 4; ++n)
            b[n] = *reinterpret_cast<const bf16x8*>(&cur[(col0 + n * 16 + lr) * 32 + 8 * lg]);
#pragma unroll
        for (int m = 0; m < 4; ++m)
            a[m] = *reinterpret_cast<const bf16x8*>(
                &As[(r0 + m * 16 + lr) * LDA + ((s * 32 + 8 * lg) ^ sw)]);
        __builtin_amdgcn_s_setprio(1);
#pragma unroll
        for (int m = 0; m < 4; ++m)
#pragma unroll
            for (int n = 0; n < 4; ++n)
                acc[m][n] = __builtin_amdgcn_mfma_f32_16x16x32_bf16(a[m], b[n], acc[m][n], 0, 0, 0);
        __builtin_amdgcn_s_setprio(0);
    }
}

// MLP over 128-edge tiles; grid 256 = exactly 1 block/CU; 8 waves (512 thr).
// Wave wv: rows r0=(wv>>2)*64..+64, cols col0=(wv&3)*64..+64 (m4n4 fragments).
// D-frag lane l: row = r0 + m*16 + 4*(l>>4) + i, col = col0 + n*16 + (l&15).
// LDS 144 KB; VGPR cap 256 at 2 waves/SIMD -> no spill at ~180 demand.
__global__ __launch_bounds__(512, 1) void mlp_k(const unsigned short* __restrict__ xij_g,
                                                const unsigned short* __restrict__ xcn_g,
                                                const unsigned short* __restrict__ WT,
                                                const float* __restrict__ xij_b1,
                                                const float* __restrict__ xij_b2,
                                                const float* __restrict__ xcn_b1,
                                                const float* __restrict__ xcn_b2,
                                                const float* __restrict__ xcn_b3,
                                                const float* __restrict__ lin_b1,
                                                const float* __restrict__ lin_w2,
                                                const float* __restrict__ lin_b2,
                                                const float* __restrict__ beta,
                                                float* __restrict__ out) {
    __shared__ unsigned short sXij[128 * 64];   // 16 KB, pre-swizzled (aliased as sRed later)
    __shared__ unsigned short sXcn[128 * 64];   // 16 KB, pre-swizzled
    __shared__ unsigned short sH[128 * 256];    // 64 KB activation (in-place reuse)
    __shared__ unsigned short sB[3 * 8192];     // 48 KB weight ring

    const int tid  = threadIdx.x;
    const int wv   = tid >> 6;
    const int lane = tid & 63;
    const int lr   = lane & 15;
    const int lg   = lane >> 4;
    const int r0   = (wv >> 2) * 64;
    const int col0 = (wv & 3) * 64;
    const int row0 = blockIdx.x * 128;

    // prologue: 8 outstanding/wave: sXij(2), sXcn(2), t0(2), t1(2).
    // P1 step0's vmcnt(2) completes sXij,sXcn,t0 (FIFO), leaves t1 in flight.
    stage_tile(xij_g + (size_t)row0 * FIN, sXij, tid, wv);
    stage_tile(xcn_g + (size_t)row0 * FIN, sXcn, tid, wv);
    stage_tile(WT + tile_off(0), sB, tid, wv);
    stage_tile(WT + tile_off(1), sB + 8192, tid, wv);
    const float betaf = beta[0];

    f32x4 acc[4][4];
    float bl[4];

    // ---- P1: h1 = relu(xij @ xij_w1 + b1) -> sH (first write, no hazard) ----
    run_phase<0, 2, 64>(sXij, sB, WT, lr, lg, col0, r0, tid, wv, acc);
#pragma unroll
    for (int n = 0; n < 4; ++n) bl[n] = xij_b1[col0 + n * 16 + lr];
#pragma unroll
    for (int m = 0; m < 4; ++m)
#pragma unroll
        for (int n = 0; n < 4; ++n)
#pragma unroll
            for (int i = 0; i < 4; ++i) {
                int row = r0 + m * 16 + 4 * lg + i;
                int col = col0 + n * 16 + lr;
                sH[row * HID + (col ^ ((row & 7) << 3))] = f2bf(fmaxf(acc[m][n][i] + bl[n], 0.f));
            }
    // writes drained+fenced by P2 step0's lgkmcnt(0)+barrier before any wave reads sH

    // ---- P2: h_ij = h1 @ xij_w2 + b2 -> registers (packed bf16, 32 VGPR) ----
    run_phase<2, 8, 256>(sH, sB, WT, lr, lg, col0, r0, tid, wv, acc);
#pragma unroll
    for (int n = 0; n < 4; ++n) bl[n] = xij_b2[col0 + n * 16 + lr];
    unsigned hij_lo[4][4], hij_hi[4][4];
#pragma unroll
    for (int m = 0; m < 4; ++m)
#pragma unroll
        for (int n = 0; n < 4; ++n) {
            hij_lo[m][n] = ((unsigned)f2bf(acc[m][n][1] + bl[n]) << 16) | f2bf(acc[m][n][0] + bl[n]);
            hij_hi[m][n] = ((unsigned)f2bf(acc[m][n][3] + bl[n]) << 16) | f2bf(acc[m][n][2] + bl[n]);
        }

    // ---- P3: t1 = relu(xcn @ xcn_w1 + b1) -> sH (all P2 sH reads fenced by P3's
    //      step-0 lgkm0+barrier before this epilogue runs) ----
    run_phase<10, 2, 64>(sXcn, sB, WT, lr, lg, col0, r0, tid, wv, acc);
#pragma unroll
    for (int n = 0; n < 4; ++n) bl[n] = xcn_b1[col0 + n * 16 + lr];
#pragma unroll
    for (int m = 0; m < 4; ++m)
#pragma unroll
        for (int n = 0; n < 4; ++n)
#pragma unroll
            for (int i = 0; i < 4; ++i) {
                int row = r0 + m * 16 + 4 * lg + i;
                int col = col0 + n * 16 + lr;
                sH[row * HID + (col ^ ((row & 7) << 3))] = f2bf(fmaxf(acc[m][n][i] + bl[n], 0.f));
            }

    // ---- P4: t2 = relu(t1 @ xcn_w2 + b2) -> sH IN PLACE: barrier before overwrite ----
    run_phase<12, 8, 256>(sH, sB, WT, lr, lg, col0, r0, tid, wv, acc);
    asm volatile("s_waitcnt lgkmcnt(0)" ::: "memory");
    __builtin_amdgcn_s_barrier();   // all waves' t1 reads done
#pragma unroll
    for (int n = 0; n < 4; ++n) bl[n] = xcn_b2[col0 + n * 16 + lr];
#pragma unroll
    for (int m = 0; m < 4; ++m)
#pragma unroll
        for (int n = 0; n < 4; ++n)
#pragma unroll
            for (int i = 0; i < 4; ++i) {
                int row = r0 + m * 16 + 4 * lg + i;
                int col = col0 + n * 16 + lr;
                sH[row * HID + (col ^ ((row & 7) << 3))] = f2bf(fmaxf(acc[m][n][i] + bl[n], 0.f));
            }

    // ---- P5: u = (t2 @ xcn_w3 + b3) * beta + h_ij -> sH IN PLACE ----
    run_phase<20, 8, 256>(sH, sB, WT, lr, lg, col0, r0, tid, wv, acc);
    asm volatile("s_waitcnt lgkmcnt(0)" ::: "memory");
    __builtin_amdgcn_s_barrier();
#pragma unroll
    for (int n = 0; n < 4; ++n) bl[n] = xcn_b3[col0 + n * 16 + lr];
#pragma unroll
    for (int m = 0; m < 4; ++m)
#pragma unroll
        for (int n = 0; n < 4; ++n) {
            float h0 = b2f((unsigned short)(hij_lo[m][n] & 0xFFFF));
            float h1 = b2f((unsigned short)(hij_lo[m][n] >> 16));
            float h2 = b2f((unsigned short)(hij_hi[m][n] & 0xFFFF));
            float h3 = b2f((unsigned short)(hij_hi[m][n] >> 16));
            float v0 = (acc[m][n][0] + bl[n]) * betaf + h0;
            float v1 = (acc[m][n][1] + bl[n]) * betaf + h1;
            float v2 = (acc[m][n][2] + bl[n]) * betaf + h2;
            float v3 = (acc[m][n][3] + bl[n]) * betaf + h3;
            int rb = r0 + m * 16 + 4 * lg;
            int col = col0 + n * 16 + lr;
            sH[(rb + 0) * HID + (col ^ (((rb + 0) & 7) << 3))] = f2bf(v0);
            sH[(rb + 1) * HID + (col ^ (((rb + 1) & 7) << 3))] = f2bf(v1);
            sH[(rb + 2) * HID + (col ^ (((rb + 2) & 7) << 3))] = f2bf(v2);
            sH[(rb + 3) * HID + (col ^ (((rb + 3) & 7) << 3))] = f2bf(v3);
        }

    // ---- P6: out = relu(u @ lin_w1 + lb1) . lin_w2 + lb2 ----
    run_phase<28, 8, 256>(sH, sB, WT, lr, lg, col0, r0, tid, wv, acc);
#pragma unroll
    for (int n = 0; n < 4; ++n) bl[n] = lin_b1[col0 + n * 16 + lr];
    float w2l[4];
#pragma unroll
    for (int n = 0; n < 4; ++n) w2l[n] = lin_w2[col0 + n * 16 + lr];
    float* sRed = (float*)sXij;   // sXij dead since P1; 4 col-groups x 128 rows f32
#pragma unroll
    for (int m = 0; m < 4; ++m) {
        float p[4] = {0.f, 0.f, 0.f, 0.f};
#pragma unroll
        for (int n = 0; n < 4; ++n)
#pragma unroll
            for (int i = 0; i < 4; ++i)
                p[i] += fmaxf(acc[m][n][i] + bl[n], 0.f) * w2l[n];
#pragma unroll
        for (int i = 0; i < 4; ++i) {
            float s = p[i];
            s += __shfl_xor(s, 1);
            s += __shfl_xor(s, 2);
            s += __shfl_xor(s, 4);
            s += __shfl_xor(s, 8);
            if (lr == 0) sRed[(wv & 3) * 128 + r0 + m * 16 + 4 * lg + i] = s;
        }
    }
    __syncthreads();   // stream drained (P6 last step waited vmcnt(0)); plain barrier OK
    if (tid < 128)
        out[row0 + tid] = sRed[tid] + sRed[128 + tid] + sRed[256 + tid] + sRed[384 + tid] + lin_b2[0];
}

extern "C" void kernel_launch(void* const* d_in, const int* in_sizes, int n_in,
                              void* d_out, int out_size, void* d_ws, size_t ws_size,
                              hipStream_t stream) {
    const float* x      = (const float*)d_in[0];
    const int*   adj    = (const int*)d_in[1];
    const int*   tar    = (const int*)d_in[2];
    const float* beta   = (const float*)d_in[3];
    const float* xcn_w1 = (const float*)d_in[4];
    const float* xcn_b1 = (const float*)d_in[5];
    const float* xcn_w2 = (const float*)d_in[6];
    const float* xcn_b2 = (const float*)d_in[7];
    const float* xcn_w3 = (const float*)d_in[8];
    const float* xcn_b3 = (const float*)d_in[9];
    const float* xij_w1 = (const float*)d_in[10];
    const float* xij_b1 = (const float*)d_in[11];
    const float* xij_w2 = (const float*)d_in[12];
    const float* xij_b2 = (const float*)d_in[13];
    const float* lin_w1 = (const float*)d_in[14];
    const float* lin_b1 = (const float*)d_in[15];
    const float* lin_w2 = (const float*)d_in[16];
    const float* lin_b2 = (const float*)d_in[17];

    unsigned short* WT    = (unsigned short*)d_ws;                     // 576 KiB
    unsigned short* xij_g = (unsigned short*)((char*)d_ws + 589824);   // 4 MiB
    unsigned short* xcn_g = (unsigned short*)((char*)d_ws + 4784128);  // 4 MiB

    edge_prep_k<<<NEDGES / 4, 256, 0, stream>>>(x, adj, tar,
                                                xij_w1, xij_w2, xcn_w1, xcn_w2, xcn_w3, lin_w1,
                                                WT, xij_g, xcn_g);
    mlp_k<<<NEDGES / 128, 512, 0, stream>>>(xij_g, xcn_g, WT,
                                            xij_b1, xij_b2, xcn_b1, xcn_b2, xcn_b3,
                                            lin_b1, lin_w2, lin_b2, beta, (float*)d_out);
}

// Round 13
// 59.254 us; speedup vs baseline: 1.2224x; 1.0564x over previous
//
#include <hip/hip_runtime.h>

// Problem constants (from reference)
#define NNODES 10000
#define DDEG   64
#define NEDGES 32768
#define FIN    64
#define HID    256

typedef __attribute__((ext_vector_type(8))) __bf16 bf16x8;
typedef __attribute__((ext_vector_type(4))) float  f32x4;

__device__ __forceinline__ unsigned short f2bf(float f) {
    unsigned x = __float_as_uint(f);
    return (unsigned short)((x + 0x7FFFu + ((x >> 16) & 1u)) >> 16);  // RNE
}
__device__ __forceinline__ float b2f(unsigned short u) {
    return __uint_as_float(((unsigned)u) << 16);
}

// Blocked transposed-weight layout (bf16): WT[k>>5][n][k&31], tile = 8192 elems (16KB).
#define OFF_XIJ1 0        // K=64  : tiles 0..1
#define OFF_XIJ2 16384    // K=256 : tiles 2..9
#define OFF_XCN1 81920    // tiles 10..11
#define OFF_XCN2 98304    // tiles 12..19
#define OFF_XCN3 163840   // tiles 20..27
#define OFF_LIN1 229376   // tiles 28..35
#define WT_TOTAL 294912
#define NTILES   36
#define NSS_ALL  18       // 18 supersteps of 2 tiles; phases never straddle a pair

__host__ __device__ constexpr int tile_off(int t) {
    return t < 2  ? OFF_XIJ1 + t * 8192
         : t < 10 ? OFF_XIJ2 + (t - 2) * 8192
         : t < 12 ? OFF_XCN1 + (t - 10) * 8192
         : t < 20 ? OFF_XCN2 + (t - 12) * 8192
         : t < 28 ? OFF_XCN3 + (t - 20) * 8192
         :          OFF_LIN1 + (t - 28) * 8192;
}

// ---- async global->LDS (LDS dest = wave-uniform base + lane*16B) ----
__device__ __forceinline__ void gll16(const unsigned short* g, unsigned short* l) {
    __builtin_amdgcn_global_load_lds(
        (const __attribute__((address_space(1))) unsigned int*)g,
        (__attribute__((address_space(3))) unsigned int*)l, 16, 0, 0);
}
// 16KB tile with 512 threads: 2 gll16/thread
__device__ __forceinline__ void stage_tile(const unsigned short* g, unsigned short* l,
                                           int tid, int wv) {
#pragma unroll
    for (int c = 0; c < 2; ++c)
        gll16(g + c * 4096 + tid * 8, l + c * 4096 + wv * 512);
}
// 32KB tile PAIR (tiles 2g,2g+1 are contiguous in WT within a phase; dest slot pair
// ((2g)&3) is contiguous in the 4-slot ring): 4 gll16/thread
__device__ __forceinline__ void stage_pair(const unsigned short* __restrict__ WT, int g,
                                           unsigned short* ring, int tid, int wv) {
    const unsigned short* src = WT + tile_off(2 * g);
    unsigned short* dst = ring + ((2 * g) & 3) * 8192;
#pragma unroll
    for (int c = 0; c < 4; ++c)
        gll16(src + c * 4096 + tid * 8, dst + c * 4096 + wv * 512);
}

// Edge stage (1 edge per wave, latency TLP-hidden at 8192 blocks) + weight-prep piggyback.
// xij/xcn written PRE-SWIZZLED (elem ^= (row&7)<<3) so linear global_load_lds staging
// lands in the swizzled layout the mlp A-fragment ds_reads expect.
__global__ __launch_bounds__(256) void edge_prep_k(const float* __restrict__ x,
                                                   const int* __restrict__ adj,
                                                   const int* __restrict__ tar,
                                                   const float* __restrict__ xij_w1,
                                                   const float* __restrict__ xij_w2,
                                                   const float* __restrict__ xcn_w1,
                                                   const float* __restrict__ xcn_w2,
                                                   const float* __restrict__ xcn_w3,
                                                   const float* __restrict__ lin_w1,
                                                   unsigned short* __restrict__ WT,
                                                   unsigned short* __restrict__ xij_g,
                                                   unsigned short* __restrict__ xcn_g) {
    const int wv   = threadIdx.x >> 6;
    const int lane = threadIdx.x & 63;
    const int e    = blockIdx.x * 4 + wv;      // grid = NEDGES/4 = 8192

    int i = tar[e];
    int j = tar[NEDGES + e];
    int ni = adj[i * DDEG + lane];
    int nj = adj[j * DDEG + lane];
    float xi = x[i * FIN + lane];
    float xj = x[j * FIN + lane];

    bool found = false;
#pragma unroll
    for (int b = 0; b < 64; ++b)
        found |= (ni == (int)__builtin_amdgcn_readlane(nj, b));
    unsigned long long m = __ballot(found);

    float acc = 0.f;
    while (m) {
        int a = __ffsll(m) - 1;
        m &= m - 1;
        int r = (int)__builtin_amdgcn_readlane(ni, a);
        acc += x[r * FIN + lane];
    }
    int sl = lane ^ ((e & 7) << 3);            // pre-swizzle (row&7 == e&7)
    xij_g[(size_t)e * FIN + sl] = f2bf(xi * xj);
    xcn_g[(size_t)e * FIN + sl] = f2bf(acc);

    // ---- weight-prep piggyback: fp32 W[K,256] -> blocked bf16 WT ----
    if (blockIdx.x < WT_TOTAL / 256) {
        int idx = blockIdx.x * 256 + threadIdx.x;
        const float* src;
        int r;
        if (idx < OFF_XIJ2)      { r = idx - OFF_XIJ1; src = xij_w1; }
        else if (idx < OFF_XCN1) { r = idx - OFF_XIJ2; src = xij_w2; }
        else if (idx < OFF_XCN2) { r = idx - OFF_XCN1; src = xcn_w1; }
        else if (idx < OFF_XCN3) { r = idx - OFF_XCN2; src = xcn_w2; }
        else if (idx < OFF_LIN1) { r = idx - OFF_XCN3; src = xcn_w3; }
        else                     { r = idx - OFF_LIN1; src = lin_w1; }
        int kb  = r >> 13;
        int n   = (r & 8191) >> 5;
        int klo = r & 31;
        WT[idx] = f2bf(src[(kb * 32 + klo) * HID + n]);
    }
}

// One phase of the 18-superstep stream. 4-slot ring (2 pairs double-buffered),
// ONE barrier per superstep (2 k-tiles). Superstep g:
//   s_waitcnt vmcnt(0) lgkmcnt(0)  // pair g landed (staged at SS g-1, ~1 superstep ago);
//                                  // own prior ds ops drained before barrier
//   s_barrier                      // all waves ready; WAR on pair g+1's slots safe
//   stage pair g+1 (4 loads)       // has the whole superstep to land
//   [optional: restage sX <- xcn at P2's first superstep]
//   2x { ds_read B(4)+A(4); 16 MFMA (setprio) }
// acc[4][4]: wave tile rows r0..r0+64, cols col0..col0+64.
template <int G0, int NSS, int LDA>
__device__ __forceinline__ void run_phase(const unsigned short* As,
                                          unsigned short* ring,
                                          const unsigned short* __restrict__ WT,
                                          const unsigned short* __restrict__ restage_src,
                                          unsigned short* sX,
                                          int lr, int lg, int col0, int r0,
                                          int tid, int wv, f32x4 acc[4][4]) {
#pragma unroll
    for (int m = 0; m < 4; ++m)
#pragma unroll
        for (int n = 0; n < 4; ++n) acc[m][n] = (f32x4){0.f, 0.f, 0.f, 0.f};
    const int sw = (lr & 7) << 3;
#pragma unroll
    for (int ss = 0; ss < NSS; ++ss) {
        const int g = G0 + ss;
        asm volatile("s_waitcnt vmcnt(0) lgkmcnt(0)" ::: "memory");
        __builtin_amdgcn_s_barrier();
        if (g + 1 < NSS_ALL)
            stage_pair(WT, g + 1, ring, tid, wv);
        if (restage_src && ss == 0)
            stage_tile(restage_src, sX, tid, wv);   // xij reads done by all waves (barrier)
#pragma unroll
        for (int half = 0; half < 2; ++half) {
            const int t  = 2 * g + half;
            const int kk = (ss * 2 + half) * 32;
            const unsigned short* cur = ring + (t & 3) * 8192;
            bf16x8 a[4], b[4];
#pragma unroll
            for (int n = 0; n < 4; ++n)
                b[n] = *reinterpret_cast<const bf16x8*>(&cur[(col0 + n * 16 + lr) * 32 + 8 * lg]);
#pragma unroll
            for (int m = 0; m < 4; ++m)
                a[m] = *reinterpret_cast<const bf16x8*>(
                    &As[(r0 + m * 16 + lr) * LDA + ((kk + 8 * lg) ^ sw)]);
            __builtin_amdgcn_s_setprio(1);
#pragma unroll
            for (int m = 0; m < 4; ++m)
#pragma unroll
                for (int n = 0; n < 4; ++n)
                    acc[m][n] = __builtin_amdgcn_mfma_f32_16x16x32_bf16(a[m], b[n], acc[m][n], 0, 0, 0);
            __builtin_amdgcn_s_setprio(0);
        }
    }
}

// MLP over 128-edge tiles; grid 256 = 1 block/CU; 8 waves (512 thr).
// Wave wv: rows r0=(wv>>2)*64..+64, cols col0=(wv&3)*64..+64 (m4n4 fragments).
// D-frag lane l: row = r0 + m*16 + 4*(l>>4) + i, col = col0 + n*16 + (l&15).
// LDS 144 KB. h_ij round-trips through hij_g (same block -> same XCD L2) instead of
// registers: frees 32 VGPR so acc[4][4] fits the 128-VGPR allocation without scratch.
__global__ __launch_bounds__(512, 1) void mlp_k(const unsigned short* __restrict__ xij_g,
                                                const unsigned short* __restrict__ xcn_g,
                                                const unsigned short* __restrict__ WT,
                                                unsigned* __restrict__ hij_g,
                                                const float* __restrict__ xij_b1,
                                                const float* __restrict__ xij_b2,
                                                const float* __restrict__ xcn_b1,
                                                const float* __restrict__ xcn_b2,
                                                const float* __restrict__ xcn_b3,
                                                const float* __restrict__ lin_b1,
                                                const float* __restrict__ lin_w2,
                                                const float* __restrict__ lin_b2,
                                                const float* __restrict__ beta,
                                                float* __restrict__ out) {
    __shared__ unsigned short sX[128 * 64];    // 16 KB: xij (P1), restaged xcn (P3); sRed later
    __shared__ unsigned short sH[128 * 256];   // 64 KB activation (in-place reuse)
    __shared__ unsigned short sB[4 * 8192];    // 64 KB weight ring (2 pairs)

    const int tid  = threadIdx.x;
    const int wv   = tid >> 6;
    const int lane = tid & 63;
    const int lr   = lane & 15;
    const int lg   = lane >> 4;
    const int r0   = (wv >> 2) * 64;
    const int col0 = (wv & 3) * 64;
    const int row0 = blockIdx.x * 128;

    // prologue: sX<-xij (2 loads) + pair0 (4 loads) = 6 outstanding/wave.
    // P1 SS0's vmcnt(0) drains all; pair1 staged at P1 SS0 top.
    stage_tile(xij_g + (size_t)row0 * FIN, sX, tid, wv);
    stage_pair(WT, 0, sB, tid, wv);
    const float betaf = beta[0];
    unsigned* hbase = hij_g + (size_t)(blockIdx.x * 8 + wv) * 2048 + lane * 2;

    f32x4 acc[4][4];
    float bl[4];

    // ---- P1 (g=0): h1 = relu(xij @ xij_w1 + b1) -> sH ----
    run_phase<0, 1, 64>(sX, sB, WT, nullptr, nullptr, lr, lg, col0, r0, tid, wv, acc);
#pragma unroll
    for (int n = 0; n < 4; ++n) bl[n] = xij_b1[col0 + n * 16 + lr];
#pragma unroll
    for (int m = 0; m < 4; ++m)
#pragma unroll
        for (int n = 0; n < 4; ++n)
#pragma unroll
            for (int i = 0; i < 4; ++i) {
                int row = r0 + m * 16 + 4 * lg + i;
                int col = col0 + n * 16 + lr;
                sH[row * HID + (col ^ ((row & 7) << 3))] = f2bf(fmaxf(acc[m][n][i] + bl[n], 0.f));
            }
    // writes fenced by P2 SS0's lgkm0+barrier before any wave reads sH

    // ---- P2 (g=1..4): h_ij = h1 @ xij_w2 + b2 -> hij_g (L2-resident round-trip);
    //      also restages sX <- xcn at SS0 (xij reads all done behind that barrier) ----
    run_phase<1, 4, 256>(sH, sB, WT, xcn_g + (size_t)row0 * FIN, sX, lr, lg, col0, r0, tid, wv, acc);
#pragma unroll
    for (int n = 0; n < 4; ++n) bl[n] = xij_b2[col0 + n * 16 + lr];
#pragma unroll
    for (int m = 0; m < 4; ++m)
#pragma unroll
        for (int n = 0; n < 4; ++n) {
            uint2 v;
            v.x = ((unsigned)f2bf(acc[m][n][1] + bl[n]) << 16) | f2bf(acc[m][n][0] + bl[n]);
            v.y = ((unsigned)f2bf(acc[m][n][3] + bl[n]) << 16) | f2bf(acc[m][n][2] + bl[n]);
            *reinterpret_cast<uint2*>(hbase + (m * 4 + n) * 128) = v;
        }

    // ---- P3 (g=5): t1 = relu(xcn @ xcn_w1 + b1) -> sH ----
    run_phase<5, 1, 64>(sX, sB, WT, nullptr, nullptr, lr, lg, col0, r0, tid, wv, acc);
#pragma unroll
    for (int n = 0; n < 4; ++n) bl[n] = xcn_b1[col0 + n * 16 + lr];
#pragma unroll
    for (int m = 0; m < 4; ++m)
#pragma unroll
        for (int n = 0; n < 4; ++n)
#pragma unroll
            for (int i = 0; i < 4; ++i) {
                int row = r0 + m * 16 + 4 * lg + i;
                int col = col0 + n * 16 + lr;
                sH[row * HID + (col ^ ((row & 7) << 3))] = f2bf(fmaxf(acc[m][n][i] + bl[n], 0.f));
            }

    // ---- P4 (g=6..9): t2 = relu(t1 @ xcn_w2 + b2) -> sH IN PLACE ----
    run_phase<6, 4, 256>(sH, sB, WT, nullptr, nullptr, lr, lg, col0, r0, tid, wv, acc);
    asm volatile("s_waitcnt lgkmcnt(0)" ::: "memory");
    __builtin_amdgcn_s_barrier();   // all waves' t1 reads done before overwrite
#pragma unroll
    for (int n = 0; n < 4; ++n) bl[n] = xcn_b2[col0 + n * 16 + lr];
#pragma unroll
    for (int m = 0; m < 4; ++m)
#pragma unroll
        for (int n = 0; n < 4; ++n)
#pragma unroll
            for (int i = 0; i < 4; ++i) {
                int row = r0 + m * 16 + 4 * lg + i;
                int col = col0 + n * 16 + lr;
                sH[row * HID + (col ^ ((row & 7) << 3))] = f2bf(fmaxf(acc[m][n][i] + bl[n], 0.f));
            }

    // ---- P5 (g=10..13): u = (t2 @ xcn_w3 + b3) * beta + h_ij -> sH IN PLACE ----
    run_phase<10, 4, 256>(sH, sB, WT, nullptr, nullptr, lr, lg, col0, r0, tid, wv, acc);
    asm volatile("s_waitcnt lgkmcnt(0)" ::: "memory");
    __builtin_amdgcn_s_barrier();
#pragma unroll
    for (int n = 0; n < 4; ++n) bl[n] = xcn_b3[col0 + n * 16 + lr];
#pragma unroll
    for (int m = 0; m < 4; ++m)
#pragma unroll
        for (int n = 0; n < 4; ++n) {
            uint2 v = *reinterpret_cast<const uint2*>(hbase + (m * 4 + n) * 128);
            float h0 = b2f((unsigned short)(v.x & 0xFFFF));
            float h1 = b2f((unsigned short)(v.x >> 16));
            float h2 = b2f((unsigned short)(v.y & 0xFFFF));
            float h3 = b2f((unsigned short)(v.y >> 16));
            float v0 = (acc[m][n][0] + bl[n]) * betaf + h0;
            float v1 = (acc[m][n][1] + bl[n]) * betaf + h1;
            float v2 = (acc[m][n][2] + bl[n]) * betaf + h2;
            float v3 = (acc[m][n][3] + bl[n]) * betaf + h3;
            int rb = r0 + m * 16 + 4 * lg;
            int col = col0 + n * 16 + lr;
            sH[(rb + 0) * HID + (col ^ (((rb + 0) & 7) << 3))] = f2bf(v0);
            sH[(rb + 1) * HID + (col ^ (((rb + 1) & 7) << 3))] = f2bf(v1);
            sH[(rb + 2) * HID + (col ^ (((rb + 2) & 7) << 3))] = f2bf(v2);
            sH[(rb + 3) * HID + (col ^ (((rb + 3) & 7) << 3))] = f2bf(v3);
        }

    // ---- P6 (g=14..17): out = relu(u @ lin_w1 + lb1) . lin_w2 + lb2 ----
    run_phase<14, 4, 256>(sH, sB, WT, nullptr, nullptr, lr, lg, col0, r0, tid, wv, acc);
#pragma unroll
    for (int n = 0; n < 4; ++n) bl[n] = lin_b1[col0 + n * 16 + lr];
    float w2l[4];
#pragma unroll
    for (int n = 0; n < 4; ++n) w2l[n] = lin_w2[col0 + n * 16 + lr];
    float* sRed = (float*)sX;   // sX dead since P3; 4 col-groups x 128 rows f32 (2KB)
#pragma unroll
    for (int m = 0; m < 4; ++m) {
        float p[4] = {0.f, 0.f, 0.f, 0.f};
#pragma unroll
        for (int n = 0; n < 4; ++n)
#pragma unroll
            for (int i = 0; i < 4; ++i)
                p[i] += fmaxf(acc[m][n][i] + bl[n], 0.f) * w2l[n];
#pragma unroll
        for (int i = 0; i < 4; ++i) {
            float s = p[i];
            s += __shfl_xor(s, 1);
            s += __shfl_xor(s, 2);
            s += __shfl_xor(s, 4);
            s += __shfl_xor(s, 8);
            if (lr == 0) sRed[(wv & 3) * 128 + r0 + m * 16 + 4 * lg + i] = s;
        }
    }
    __syncthreads();   // stream fully drained at P6 SS-last's vmcnt(0); plain barrier OK
    if (tid < 128)
        out[row0 + tid] = sRed[tid] + sRed[128 + tid] + sRed[256 + tid] + sRed[384 + tid] + lin_b2[0];
}

extern "C" void kernel_launch(void* const* d_in, const int* in_sizes, int n_in,
                              void* d_out, int out_size, void* d_ws, size_t ws_size,
                              hipStream_t stream) {
    const float* x      = (const float*)d_in[0];
    const int*   adj    = (const int*)d_in[1];
    const int*   tar    = (const int*)d_in[2];
    const float* beta   = (const float*)d_in[3];
    const float* xcn_w1 = (const float*)d_in[4];
    const float* xcn_b1 = (const float*)d_in[5];
    const float* xcn_w2 = (const float*)d_in[6];
    const float* xcn_b2 = (const float*)d_in[7];
    const float* xcn_w3 = (const float*)d_in[8];
    const float* xcn_b3 = (const float*)d_in[9];
    const float* xij_w1 = (const float*)d_in[10];
    const float* xij_b1 = (const float*)d_in[11];
    const float* xij_w2 = (const float*)d_in[12];
    const float* xij_b2 = (const float*)d_in[13];
    const float* lin_w1 = (const float*)d_in[14];
    const float* lin_b1 = (const float*)d_in[15];
    const float* lin_w2 = (const float*)d_in[16];
    const float* lin_b2 = (const float*)d_in[17];

    unsigned short* WT    = (unsigned short*)d_ws;                     // 576 KiB
    unsigned short* xij_g = (unsigned short*)((char*)d_ws + 589824);   // 4 MiB
    unsigned short* xcn_g = (unsigned short*)((char*)d_ws + 4784128);  // 4 MiB
    unsigned*       hij_g = (unsigned*)((char*)d_ws + 8978432);        // 16 MiB

    edge_prep_k<<<NEDGES / 4, 256, 0, stream>>>(x, adj, tar,
                                                xij_w1, xij_w2, xcn_w1, xcn_w2, xcn_w3, lin_w1,
                                                WT, xij_g, xcn_g);
    mlp_k<<<NEDGES / 128, 512, 0, stream>>>(xij_g, xcn_g, WT, hij_g,
                                            xij_b1, xij_b2, xcn_b1, xcn_b2, xcn_b3,
                                            lin_b1, lin_w2, lin_b2, beta, (float*)d_out);
}